// Round 1
// baseline (100.784 us; speedup 1.0000x reference)
//
#include <hip/hip_runtime.h>

#define G_TOTAL 16384   // 128 x 128 grid points
#define NPTS    8192    // context points
#define SPLIT   16      // split-K factor over context points
#define CHUNK   (NPTS / SPLIT)   // 512 points per block
#define BLOCK   256

// ---------------------------------------------------------------------------
// Kernel 0: zero the output accumulator (d_out is poisoned 0xAA by harness)
// ---------------------------------------------------------------------------
__global__ void zero_out_kernel(float* __restrict__ out, int n) {
    int i = blockIdx.x * blockDim.x + threadIdx.x;
    if (i < n) out[i] = 0.0f;
}

// ---------------------------------------------------------------------------
// Kernel 1: partial RBF sums.
//   grid = (64 grid-point blocks, 16 context chunks), block = 256 threads.
//   Each thread owns one grid point g; loops over the block's 512-point chunk
//   staged in LDS as float4 {s*x0, s*x1, y0, y1}.
//   exp(-0.5*d2) == exp2(-( (s*dx)^2 + (s*dy)^2 )), s = sqrt(0.5*log2(e)).
// ---------------------------------------------------------------------------
__global__ __launch_bounds__(BLOCK) void enc_partial_kernel(
    const float* __restrict__ X,   // (8192, 2)
    const float* __restrict__ Y,   // (8192, 2)
    float* __restrict__ out)       // (3, 16384) accumulators
{
    __shared__ float4 pts[CHUNK];

    const int g  = blockIdx.x * BLOCK + threadIdx.x;  // grid point id
    const int jj = g & 127;        // x index
    const int kk = g >> 7;         // y index (y counts DOWN from +2)

    const float s    = 0.84932184f;         // sqrt(0.5 * log2(e))
    const float step = 4.0f / 127.0f;
    const float gx = (-2.0f + step * (float)jj) * s;
    const float gy = ( 2.0f - step * (float)kk) * s;

    // ---- stage this block's context chunk into LDS (coalesced float2 loads)
    const int base = blockIdx.y * CHUNK;
    for (int t = threadIdx.x; t < CHUNK; t += BLOCK) {
        const int i = base + t;
        float2 xv = ((const float2*)X)[i];
        float2 yv = ((const float2*)Y)[i];
        pts[t] = make_float4(xv.x * s, xv.y * s, yv.x, yv.y);
    }
    __syncthreads();

    // ---- main loop: 512 iterations, ds_read_b128 + ~8 VALU + v_exp each
    float a0 = 0.0f, a1 = 0.0f, a2 = 0.0f;
#pragma unroll 8
    for (int t = 0; t < CHUNK; ++t) {
        float4 p = pts[t];                 // broadcast read (same addr all lanes)
        float dx = gx - p.x;
        float dy = gy - p.y;
        float arg = fmaf(dx, dx, dy * dy); // (dx^2 + dy^2), already log2e-scaled
        float w = exp2f(-arg);             // v_exp_f32, negate is free src mod
        a0 += w;
        a1 = fmaf(w, p.z, a1);
        a2 = fmaf(w, p.w, a2);
    }

    // ---- accumulate partials (16 blocks contend per address — negligible)
    atomicAdd(&out[g],               a0);
    atomicAdd(&out[G_TOTAL + g],     a1);
    atomicAdd(&out[2 * G_TOTAL + g], a2);
}

// ---------------------------------------------------------------------------
// Kernel 2: normalize smoothing channels by density channel, in place.
// ---------------------------------------------------------------------------
__global__ void normalize_kernel(float* __restrict__ out) {
    int g = blockIdx.x * blockDim.x + threadIdx.x;
    if (g < G_TOTAL) {
        float inv = 1.0f / out[g];
        out[G_TOTAL + g]     *= inv;
        out[2 * G_TOTAL + g] *= inv;
    }
}

// ---------------------------------------------------------------------------
extern "C" void kernel_launch(void* const* d_in, const int* in_sizes, int n_in,
                              void* d_out, int out_size, void* d_ws, size_t ws_size,
                              hipStream_t stream) {
    const float* X = (const float*)d_in[0];
    const float* Y = (const float*)d_in[1];
    float* out = (float*)d_out;

    zero_out_kernel<<<(3 * G_TOTAL + 255) / 256, 256, 0, stream>>>(out, 3 * G_TOTAL);

    dim3 grid(G_TOTAL / BLOCK, SPLIT);
    enc_partial_kernel<<<grid, BLOCK, 0, stream>>>(X, Y, out);

    normalize_kernel<<<(G_TOTAL + 255) / 256, 256, 0, stream>>>(out);
}